// Round 3
// baseline (3999.010 us; speedup 1.0000x reference)
//
#include <hip/hip_runtime.h>
#include <hip/hip_bf16.h>

#define NN 1024
#define BT 64          // tile size
#define TT 16          // tiles per dim
#define PR 24          // traceback patch rows
#define PC 24          // traceback patch cols

// ---------------------------------------------------------------------------
// primes[i] = BASE_PRIMES[argmax_ch feat[0, ch, i, 0]]  (first-max)
// ---------------------------------------------------------------------------
__global__ void primes_kernel(const float* __restrict__ feat, int* __restrict__ primes) {
    int i = blockIdx.x * blockDim.x + threadIdx.x;
    if (i < NN) {
        float best = feat[i * NN];
        int arg = 0;
        for (int ch = 1; ch < 4; ++ch) {
            float v = feat[ch * NN * NN + i * NN];
            if (v > best) { best = v; arg = ch; }
        }
        const int P[4] = {2, 3, 5, 7};
        primes[i] = P[arg];
    }
}

// ---------------------------------------------------------------------------
// S = premask(con); zero R, C, out
// ---------------------------------------------------------------------------
__global__ void prep_kernel(const float* __restrict__ con, const int* __restrict__ primes,
                            float* __restrict__ S, double* __restrict__ R,
                            double* __restrict__ C, float* __restrict__ out) {
    int idx = blockIdx.x * blockDim.x + threadIdx.x;
    int i = idx >> 10;
    int j = idx & (NN - 1);
    float c = (con[idx] + con[j * NN + i]) * 0.5f;
    int prod = primes[i] * primes[j];
    bool canon = (prod == 14) | (prod == 15) | (prod == 35);
    int d = i - j; if (d < 0) d = -d;
    S[idx] = (canon && d >= 4) ? c : 0.0f;
    R[idx] = 0.0;
    C[idx] = 0.0;
    out[idx] = 0.0f;
}

// ---------------------------------------------------------------------------
// dd=0: diagonal 64x64 tiles, fully in LDS. One workgroup per tile.
// ---------------------------------------------------------------------------
__global__ __launch_bounds__(256) void diag_tiles_kernel(double* __restrict__ R,
                                                         double* __restrict__ C,
                                                         const float* __restrict__ S) {
    __shared__ double VT[64][65];
    __shared__ float  SSt[64][64];
    int a = blockIdx.x * BT;
    int tid = threadIdx.x;
    for (int idx = tid; idx < 4096; idx += 256) {
        int r = idx >> 6, c = idx & 63;
        VT[r][c] = 0.0;
        SSt[r][c] = S[(a + r) * NN + a + c];
    }
    __syncthreads();
    int cell = tid >> 2, sub = tid & 3;
    for (int d = 1; d < 64; ++d) {
        int r = cell;
        if (r + d < 64) {
            int c = r + d;
            double acc = -1.0;
            for (int kk = r + sub; kk < c; kk += 4)
                acc = fmax(acc, VT[r][kk] + VT[kk + 1][c]);
            acc = fmax(acc, __shfl_xor(acc, 1));
            acc = fmax(acc, __shfl_xor(acc, 2));
            if (sub == 0) {
                acc = fmax(acc, VT[r + 1][c - 1] + (double)SSt[r][c]);
                VT[r][c] = acc;
            }
        }
        __syncthreads();
    }
    for (int idx = tid; idx < 4096; idx += 256) {
        int r = idx >> 6, c = idx & 63;
        R[(a + r) * NN + a + c] = VT[r][c];
        C[(a + c) * NN + a + r] = VT[r][c];
    }
}

// ---------------------------------------------------------------------------
// Phase A: external split contributions for tile (I, J=I+dd), one block per
// (tile, interior k-tile). Max-plus 64x64x64 into Pbuf[blockIdx].
// ---------------------------------------------------------------------------
__global__ __launch_bounds__(256) void phaseA_kernel(const double* __restrict__ R,
                                                     const double* __restrict__ C,
                                                     double* __restrict__ Pbuf, int dd) {
    int nk = dd - 1;
    int t = blockIdx.x / nk;
    int kt = blockIdx.x - t * nk;
    int aI = t * BT;
    int aJ = (t + dd) * BT;
    int kb = (t + 1 + kt) * BT;
    __shared__ double Ast[64][65];   // Ast[kk][r] = V(aI+r, kb+kk)
    __shared__ double Bst[64][65];   // Bst[kk][c] = V(kb+kk+1, aJ+c)
    int tid = threadIdx.x;
    for (int idx = tid; idx < 4096; idx += 256) {
        int r = idx >> 6, kk = idx & 63;
        Ast[kk][r] = R[(aI + r) * NN + kb + kk];
        Bst[kk][r] = C[(aJ + r) * NN + kb + 1 + kk];
    }
    __syncthreads();
    int r4 = (tid >> 4) << 2;
    int c4 = (tid & 15) << 2;
    double acc[4][4];
    for (int x = 0; x < 4; ++x) for (int y = 0; y < 4; ++y) acc[x][y] = -1.0;
    for (int kk = 0; kk < 64; ++kk) {
        double av[4], bv[4];
        for (int x = 0; x < 4; ++x) av[x] = Ast[kk][r4 + x];
        for (int y = 0; y < 4; ++y) bv[y] = Bst[kk][c4 + y];
        for (int x = 0; x < 4; ++x)
            for (int y = 0; y < 4; ++y)
                acc[x][y] = fmax(acc[x][y], av[x] + bv[y]);
    }
    double* P = Pbuf + (size_t)blockIdx.x * 4096;
    for (int x = 0; x < 4; ++x)
        for (int y = 0; y < 4; ++y)
            P[(r4 + x) * 64 + c4 + y] = acc[x][y];
}

// ---------------------------------------------------------------------------
// Phase B: intra-tile coupling, 127 anti-diagonal micro-steps.
// Lane group (4 lanes) permanently owns row r; DII row slice and the V-row
// live in REGISTERS (halves LDS traffic vs R2). Exact candidate set preserved
// (bitwise-identical to numpy: each candidate is one fp64 add of stored
// values; fmax order-insensitive).
// ---------------------------------------------------------------------------
__global__ __launch_bounds__(256) void phaseB_kernel(double* __restrict__ R,
                                                     double* __restrict__ C,
                                                     const float* __restrict__ S,
                                                     const double* __restrict__ Pbuf, int dd) {
    __shared__ double DJJt[64][67];   // DJJt[c][m] = V(aJ+m, aJ+c)
    __shared__ double VTc[64][67];    // VTc[c][r] = V(aI+r, aJ+c)
    __shared__ double PT[64][64];     // external split max
    __shared__ float  SSt[64][64];
    __shared__ double edgeRow[64];    // V(aI+64, aJ+c)
    __shared__ double edgeCol[64];    // V(aI+r, aJ-1)
    __shared__ double cornerv;        // V(aI+64, aJ-1)
    int t = blockIdx.x;
    int aI = t * BT, aJ = (t + dd) * BT;
    int tid = threadIdx.x;
    int nk = dd - 1;
    for (int idx = tid; idx < 4096; idx += 256) {
        int a = idx >> 6, b = idx & 63;
        DJJt[a][b] = C[(aJ + a) * NN + aJ + b];
        SSt[a][b]  = S[(aI + a) * NN + aJ + b];
        double p = -1.0;
        for (int q = 0; q < nk; ++q)
            p = fmax(p, Pbuf[(size_t)(t * nk + q) * 4096 + idx]);
        PT[a][b] = p;
    }
    if (tid < 64) {
        edgeRow[tid] = R[(aI + 64) * NN + aJ + tid];
        edgeCol[tid] = C[(aJ - 1) * NN + aI + tid];
    }
    if (tid == 0) cornerv = C[(aJ - 1) * NN + aI + 64];

    int r = tid >> 2, sub = tid & 3;
    double aslice[16], vrow[16];
    #pragma unroll
    for (int u = 0; u < 16; ++u) {
        int kk = r + sub + 4 * u;
        aslice[u] = (kk <= 63) ? R[(aI + r) * NN + aI + kk] : 0.0;
        vrow[u] = 0.0;
    }
    double dii63 = R[(aI + r) * NN + aI + 63];
    __syncthreads();

    for (int s = 0; s < 127; ++s) {
        int c = r + s - 63;
        bool active = (unsigned)c < 64u;
        double acc = -1.0;
        if (active) {
            #pragma unroll
            for (int u = 0; u < 16; ++u) {
                int kk = r + sub + 4 * u;
                if (kk <= 62) acc = fmax(acc, aslice[u] + VTc[c][kk + 1]);
            }
            #pragma unroll
            for (int u = 0; u < 16; ++u) {
                int m = sub + 1 + 4 * u;
                if (m <= c) acc = fmax(acc, vrow[u] + DJJt[c][m]);
            }
        }
        acc = fmax(acc, __shfl_xor(acc, 1));
        acc = fmax(acc, __shfl_xor(acc, 2));
        if (active) {
            double best = acc;
            best = fmax(best, dii63 + edgeRow[c]);          // k = bI (=aI+63)
            best = fmax(best, edgeCol[r] + DJJt[c][0]);     // k = aJ-1
            best = fmax(best, PT[r][c]);                    // external splits
            double pv;
            if (r < 63) pv = (c > 0) ? VTc[c - 1][r + 1] : edgeCol[r + 1];
            else        pv = (c > 0) ? edgeRow[c - 1] : cornerv;
            best = fmax(best, pv + (double)SSt[r][c]);      // pair
            if (sub == 0) VTc[c][r] = best;
            #pragma unroll
            for (int u = 0; u < 16; ++u)
                if (c == 4 * u + sub) vrow[u] = best;
        }
        __syncthreads();
    }

    for (int idx = tid; idx < 4096; idx += 256) {
        int rr = idx >> 6, cc = idx & 63;
        R[(aI + rr) * NN + aJ + cc] = VTc[cc][rr];
    }
    for (int idx = tid; idx < 4096; idx += 256) {
        int cc = idx >> 6, rr = idx & 63;
        C[(aJ + cc) * NN + aI + rr] = VTc[cc][rr];
    }
}

// ---------------------------------------------------------------------------
// Traceback with LDS patch caching. Non-split events only move (i,j) to
// (i+1,j) or (i+1,j-1): thread 0 runs up to ~PR events per patch with zero
// global latency. Splits use the block-parallel first-max argmax.
// ---------------------------------------------------------------------------
__global__ __launch_bounds__(256) void traceback_kernel(const double* __restrict__ R,
                                                        const double* __restrict__ C,
                                                        const float* __restrict__ S,
                                                        float* __restrict__ out) {
    __shared__ int stk_i[2048];
    __shared__ int stk_j[2048];
    __shared__ double stk_v[2048];
    __shared__ double LR[PR + 1][PC + 1];
    __shared__ float  LS[PR][PC];
    __shared__ int sh_cmd, sh_i, sh_j, sh_top;
    __shared__ double sh_v;
    __shared__ double sred_v[4];
    __shared__ int sred_k[4];
    const double eps = 1e-9;
    int tid = threadIdx.x;
    if (tid == 0) {
        stk_i[0] = 0; stk_j[0] = NN - 1; stk_v[0] = R[NN - 1];
        sh_top = 1;
    }
    __syncthreads();
    // cmd: 0 = patch loaded/process, 1 = split, 2 = done, 3 = reload
    while (true) {
        if (tid == 0) {               // stage A: pop until workable
            int top = sh_top, cmd = 2;
            while (top > 0) {
                int i = stk_i[--top];
                int j = stk_j[top];
                double v = stk_v[top];
                if (j <= i || v <= eps) continue;
                sh_i = i; sh_j = j; sh_v = v; cmd = 0;
                break;
            }
            sh_top = top; sh_cmd = cmd;
        }
        __syncthreads();
        if (sh_cmd == 2) break;
        int bi = sh_i, bj = sh_j;
        for (int idx = tid; idx < (PR + 1) * (PC + 1); idx += 256) {
            int di = idx / (PC + 1), dj = idx % (PC + 1);
            int row = bi + di; if (row > NN - 1) row = NN - 1;
            int col = bj - PC + dj;
            LR[di][dj] = (col >= 0) ? R[row * NN + col] : 0.0;
        }
        for (int idx = tid; idx < PR * PC; idx += 256) {
            int di = idx / PC, djm = idx % PC;
            int row = bi + di; if (row > NN - 1) row = NN - 1;
            int col = bj - PC + 1 + djm;
            LS[di][djm] = (col >= 0) ? S[row * NN + col] : 0.0f;
        }
        __syncthreads();
        if (tid == 0) {               // stage B: process events in-patch
            int i = sh_i, j = sh_j, top = sh_top, cmd;
            double v = sh_v;
            while (true) {
                if (j <= i || v <= eps) {
                    if (top == 0) { cmd = 2; break; }
                    i = stk_i[--top]; j = stk_j[top]; v = stk_v[top];
                    if (j <= i || v <= eps) continue;
                    stk_i[top] = i; stk_j[top] = j; stk_v[top] = v; ++top;
                    cmd = 3; break;   // re-anchor patch at popped entry
                }
                if ((i - bi) >= PR || (bj - j) >= PC) {
                    stk_i[top] = i; stk_j[top] = j; stk_v[top] = v; ++top;
                    cmd = 3; break;   // left the patch
                }
                int di = i - bi, dj = j - (bj - PC);
                double a = LR[di + 1][dj];
                float sv = LS[di][dj - 1];
                double b = LR[di + 1][dj - 1];
                if (a >= v - eps) { ++i; v = a; continue; }
                if (sv > 0.0f && b + (double)sv >= v - eps) {
                    out[i * NN + j] = sv; out[j * NN + i] = sv;
                    ++i; --j; v = b; continue;
                }
                sh_i = i; sh_j = j; cmd = 1; break;   // split needed
            }
            sh_top = top; sh_cmd = cmd;
        }
        __syncthreads();
        if (sh_cmd == 2) break;
        if (sh_cmd == 1) {
            int i = sh_i, j = sh_j;
            double bv = -1.0; int bk = 0x7fffffff;
            for (int k = i + tid; k < j; k += 256) {
                double tv = R[i * NN + k] + C[j * NN + k + 1];
                if (tv > bv) { bv = tv; bk = k; }
            }
            for (int off = 32; off; off >>= 1) {
                double ov = __shfl_down(bv, off);
                int    ok = __shfl_down(bk, off);
                if (ov > bv || (ov == bv && ok < bk)) { bv = ov; bk = ok; }
            }
            if ((tid & 63) == 0) { sred_v[tid >> 6] = bv; sred_k[tid >> 6] = bk; }
            __syncthreads();
            if (tid == 0) {
                double fv = sred_v[0]; int fk = sred_k[0];
                for (int w = 1; w < 4; ++w)
                    if (sred_v[w] > fv || (sred_v[w] == fv && sred_k[w] < fk)) { fv = sred_v[w]; fk = sred_k[w]; }
                int i0 = sh_i, j0 = sh_j, top = sh_top;
                stk_i[top] = i0;     stk_j[top] = fk; stk_v[top] = R[i0 * NN + fk];     ++top;
                stk_i[top] = fk + 1; stk_j[top] = j0; stk_v[top] = C[j0 * NN + fk + 1]; ++top;
                sh_top = top;
            }
            __syncthreads();
        }
    }
}

// ---------------------------------------------------------------------------
extern "C" void kernel_launch(void* const* d_in, const int* in_sizes, int n_in,
                              void* d_out, int out_size, void* d_ws, size_t ws_size,
                              hipStream_t stream) {
    const float* con  = (const float*)d_in[0];
    const float* feat = (const float*)d_in[1];
    float* out = (float*)d_out;

    char* ws = (char*)d_ws;
    double* R      = (double*)(ws);
    double* C      = (double*)(ws + (size_t)8  * 1024 * 1024);
    float*  S      = (float*) (ws + (size_t)16 * 1024 * 1024);
    int*    primes = (int*)   (ws + (size_t)20 * 1024 * 1024);
    double* Pbuf   = (double*)(ws + (size_t)20 * 1024 * 1024 + 65536);

    primes_kernel<<<(NN + 255) / 256, 256, 0, stream>>>(feat, primes);
    prep_kernel<<<(NN * NN) / 256, 256, 0, stream>>>(con, primes, S, R, C, out);
    diag_tiles_kernel<<<TT, 256, 0, stream>>>(R, C, S);

    for (int dd = 1; dd < TT; ++dd) {
        if (dd >= 2)
            phaseA_kernel<<<(TT - dd) * (dd - 1), 256, 0, stream>>>(R, C, Pbuf, dd);
        phaseB_kernel<<<TT - dd, 256, 0, stream>>>(R, C, S, Pbuf, dd);
    }

    traceback_kernel<<<1, 256, 0, stream>>>(R, C, S, out);
}

// Round 4
// 2547.409 us; speedup vs baseline: 1.5698x; 1.5698x over previous
//
#include <hip/hip_runtime.h>
#include <hip/hip_bf16.h>

#define NN 1024
#define BT 32
#define TT 32
#define NTILES ((TT * (TT + 1)) / 2)   // 528

// ---------------------------------------------------------------------------
// device-scope flag helpers (cross-XCD safe: AGENT scope acquire/release)
// ---------------------------------------------------------------------------
__device__ __forceinline__ int ldflag(const int* f, int a, int b) {
    return __hip_atomic_load(&f[a * TT + b], __ATOMIC_ACQUIRE, __HIP_MEMORY_SCOPE_AGENT);
}
__device__ __forceinline__ void stflag(int* f, int a, int b) {
    __hip_atomic_store((int*)&f[a * TT + b], 1, __ATOMIC_RELEASE, __HIP_MEMORY_SCOPE_AGENT);
}

// ---------------------------------------------------------------------------
// primes[i] = BASE_PRIMES[argmax_ch feat[0, ch, i, 0]]  (first-max)
// ---------------------------------------------------------------------------
__global__ void primes_kernel(const float* __restrict__ feat, int* __restrict__ primes) {
    int i = blockIdx.x * blockDim.x + threadIdx.x;
    if (i < NN) {
        float best = feat[i * NN];
        int arg = 0;
        for (int ch = 1; ch < 4; ++ch) {
            float v = feat[ch * NN * NN + i * NN];
            if (v > best) { best = v; arg = ch; }
        }
        const int P[4] = {2, 3, 5, 7};
        primes[i] = P[arg];
    }
}

// ---------------------------------------------------------------------------
// S = premask(con); zero R, C, out, flags
// ---------------------------------------------------------------------------
__global__ void prep_kernel(const float* __restrict__ con, const int* __restrict__ primes,
                            float* __restrict__ S, double* __restrict__ R,
                            double* __restrict__ C, float* __restrict__ out,
                            int* __restrict__ flags) {
    int idx = blockIdx.x * blockDim.x + threadIdx.x;
    int i = idx >> 10;
    int j = idx & (NN - 1);
    float c = (con[idx] + con[j * NN + i]) * 0.5f;
    int prod = primes[i] * primes[j];
    bool canon = (prod == 14) | (prod == 15) | (prod == 35);
    int d = i - j; if (d < 0) d = -d;
    S[idx] = (canon && d >= 4) ? c : 0.0f;
    R[idx] = 0.0;
    C[idx] = 0.0;
    out[idx] = 0.0f;
    if (idx < TT * TT) flags[idx] = 0;
}

// ---------------------------------------------------------------------------
// Persistent dataflow DP: one wave per 32x32 tile (I,J). blockIdx ordered
// dd-major (topological) -> in-order HW dispatch guarantees progress even
// without full co-residency. Single wave => no __syncthreads anywhere in the
// tile solve; LDS RAW handled by same-wave ordering (lgkmcnt).
// Exactness: every candidate is one fp64 add of stored (exact) values;
// out-of-range unrolled lanes contribute dominated candidates only
// (-1e30 + x < 0 <= dp, or stale-0 + below-diag-0 = 0 <= dp). fmax is
// order-insensitive => DP bitwise == numpy.
// ---------------------------------------------------------------------------
__global__ __launch_bounds__(64) void nuss_tiles_kernel(double* __restrict__ R,
                                                        double* __restrict__ C,
                                                        const float* __restrict__ S,
                                                        int* __restrict__ flags) {
    __shared__ double DJJc[32][34];   // DJJc[c][m] = V(aJ+m, aJ+c); m=32,33 -> 0
    __shared__ double Vtc[32][34];    // Vtc[c][r]  = V(aI+r, aJ+c); col-major tile
    __shared__ double Ast[32][33];    // phaseA stage: Ast[kk][r] = V(aI+r, kt0+kk)
    __shared__ double Bst[32][33];    // phaseA stage: Bst[kk][c] = V(kt0+kk+1, aJ+c)
    __shared__ double Pld[32][33];    // external split max per cell
    __shared__ float  Sld[32][32];
    __shared__ double edgeCol[33];    // V(aI+rr, aJ-1), rr in [0,32]
    __shared__ double edgeRowF[32];   // V(aI+32, aJ+cc)

    // blockIdx -> (I, J) with dd-major order (topological)
    int b = blockIdx.x, dd = 0;
    while (b >= TT - dd) { b -= TT - dd; ++dd; }
    const int I = b, J = b + dd;
    const int aI = I * BT, aJ = J * BT;
    const int lane = threadIdx.x;
    const int r = lane >> 1;          // row owned by this lane pair
    const int h = lane & 1;           // half (owns columns/k-indices h*16..h*16+15)

    if (dd == 0) {
        // ---------------- diagonal tile: 31-step in-LDS DP ----------------
        for (int w = 0; w < 16; ++w) {
            int idx = w * 64 + lane; int rr = idx >> 5, cc = idx & 31;
            Sld[rr][cc] = S[(aI + rr) * NN + aI + cc];
        }
        for (int idx = lane; idx < 32 * 34; idx += 64)
            ((double*)Vtc)[idx] = 0.0;
        double vrow[16];
        #pragma unroll
        for (int u = 0; u < 16; ++u) vrow[u] = 0.0;

        for (int s = 1; s <= 31; ++s) {
            int c = r + s;
            bool act = (c <= 31);
            double acc = 0.0;
            if (act) {
                #pragma unroll
                for (int u = 0; u < 16; ++u) {
                    int kk = h * 16 + u;
                    // valid kk in [r, c-1]; others: stale-0 + 0 = 0 (dominated)
                    acc = fmax(acc, vrow[u] + Vtc[c][kk + 1]);
                }
            }
            acc = fmax(acc, __shfl_xor(acc, 1));
            if (act) {
                double best = fmax(acc, Vtc[c - 1][r + 1] + (double)Sld[r][c]);
                Vtc[c][r] = best;
                #pragma unroll
                for (int u = 0; u < 16; ++u)
                    if (h * 16 + u == c) vrow[u] = best;
            }
        }
        for (int w = 0; w < 16; ++w) {
            int idx = w * 64 + lane; int rr = idx >> 5, cc = idx & 31;
            R[(aI + rr) * NN + aI + cc] = Vtc[cc][rr];
        }
        for (int w = 0; w < 16; ++w) {
            int idx = w * 64 + lane; int cc = idx >> 5, rr = idx & 31;
            C[(aI + cc) * NN + aI + rr] = Vtc[cc][rr];
        }
        __threadfence();
        if (lane == 0) stflag(flags, I, I);
        return;
    }

    // ---------------- off-diagonal tile ----------------
    while (!ldflag(flags, I, I)) __builtin_amdgcn_s_sleep(2);
    while (!ldflag(flags, J, J)) __builtin_amdgcn_s_sleep(2);

    for (int w = 0; w < 16; ++w) {     // DJJc from C (coalesced)
        int idx = w * 64 + lane; int cc = idx >> 5, mm = idx & 31;
        DJJc[cc][mm] = C[(aJ + cc) * NN + aJ + mm];
    }
    if (lane < 32) { DJJc[lane][32] = 0.0; DJJc[lane][33] = 0.0; }
    for (int w = 0; w < 16; ++w) {
        int idx = w * 64 + lane; int rr = idx >> 5, cc = idx & 31;
        Sld[rr][cc] = S[(aI + rr) * NN + aJ + cc];
    }
    for (int idx = lane; idx < 32 * 34; idx += 64)
        ((double*)Vtc)[idx] = 0.0;

    // DII row slice -> registers (premask kk<r with -1e30: dominated)
    double aslice[16];
    #pragma unroll
    for (int u = 0; u < 16; ++u) {
        int kk = h * 16 + u;
        aslice[u] = (kk >= r) ? R[(aI + r) * NN + aI + kk] : -1.0e30;
    }
    double dii31 = R[(aI + r) * NN + aI + 31];

    // ---- phaseA: external k-tiles, processed as they become ready ----
    double P[16];
    #pragma unroll
    for (int x = 0; x < 16; ++x) P[x] = 0.0;
    const int nk = dd - 1;
    const int rg = lane >> 3, cg = lane & 7;
    const int r4 = rg * 4, c4 = cg * 4;
    if (nk > 0) {
        unsigned processed = 0;
        int done_cnt = 0;
        while (done_cnt < nk) {
            bool any = false;
            for (int q = 0; q < nk; ++q) {
                if (processed & (1u << q)) continue;
                int t = I + 1 + q;
                if (!ldflag(flags, I, t)) continue;
                if (!ldflag(flags, t, J)) continue;
                if (!ldflag(flags, t + 1, J)) continue;
                int kt0 = t * BT;
                for (int w = 0; w < 16; ++w) {     // stage (coalesced global)
                    int idx = w * 64 + lane; int rr = idx >> 5, kk = idx & 31;
                    Ast[kk][rr] = R[(aI + rr) * NN + kt0 + kk];
                    Bst[kk][rr] = C[(aJ + rr) * NN + kt0 + 1 + kk];
                }
                for (int kk = 0; kk < 32; ++kk) {  // 4x4 max-plus microkernel
                    double av[4], bv[4];
                    #pragma unroll
                    for (int x = 0; x < 4; ++x) av[x] = Ast[kk][r4 + x];
                    #pragma unroll
                    for (int y = 0; y < 4; ++y) bv[y] = Bst[kk][c4 + y];
                    #pragma unroll
                    for (int x = 0; x < 4; ++x)
                        #pragma unroll
                        for (int y = 0; y < 4; ++y)
                            P[x * 4 + y] = fmax(P[x * 4 + y], av[x] + bv[y]);
                }
                processed |= (1u << q); ++done_cnt; any = true;
            }
            if (!any) __builtin_amdgcn_s_sleep(2);
        }
    }
    // P regs -> LDS (per-cell external max; 0 if dd==1 — dominated candidate)
    if (nk > 0) {
        #pragma unroll
        for (int x = 0; x < 4; ++x)
            #pragma unroll
            for (int y = 0; y < 4; ++y)
                Pld[r4 + x][c4 + y] = P[x * 4 + y];
    } else {
        for (int idx = lane; idx < 32 * 33; idx += 64)
            ((double*)Pld)[idx] = 0.0;
    }

    // ---- edges from left / down neighbors ----
    while (!ldflag(flags, I, J - 1)) __builtin_amdgcn_s_sleep(2);
    if (lane < 33) edgeCol[lane] = R[(aI + lane) * NN + (aJ - 1)];
    while (!ldflag(flags, I + 1, J)) __builtin_amdgcn_s_sleep(2);
    if (lane < 32) edgeRowF[lane] = R[(aI + 32) * NN + aJ + lane];

    // ---- phaseB: 63 anti-diagonal micro-steps, barrier-free ----
    double vrow[16];
    #pragma unroll
    for (int u = 0; u < 16; ++u) vrow[u] = 0.0;

    for (int s = 0; s < 63; ++s) {
        int c = r + s - 31;
        bool act = ((unsigned)c < 32u);
        double acc = 0.0;
        if (act) {
            #pragma unroll
            for (int u = 0; u < 16; ++u) {
                int kk = h * 16 + u;
                acc = fmax(acc, aslice[u] + Vtc[c][kk + 1]);   // left splits
                acc = fmax(acc, vrow[u] + DJJc[c][kk + 1]);    // right splits
            }
        }
        acc = fmax(acc, __shfl_xor(acc, 1));
        if (act) {
            double best = acc;
            best = fmax(best, dii31 + edgeRowF[c]);            // k = aI+31
            best = fmax(best, edgeCol[r] + DJJc[c][0]);        // k = aJ-1
            best = fmax(best, Pld[r][c]);                      // external k-tiles
            double pv;
            if (r < 31) pv = (c > 0) ? Vtc[c - 1][r + 1] : edgeCol[r + 1];
            else        pv = (c > 0) ? edgeRowF[c - 1] : edgeCol[32];
            best = fmax(best, pv + (double)Sld[r][c]);         // pair
            Vtc[c][r] = best;
            #pragma unroll
            for (int u = 0; u < 16; ++u)
                if (h * 16 + u == c) vrow[u] = best;
        }
    }

    for (int w = 0; w < 16; ++w) {
        int idx = w * 64 + lane; int rr = idx >> 5, cc = idx & 31;
        R[(aI + rr) * NN + aJ + cc] = Vtc[cc][rr];
    }
    for (int w = 0; w < 16; ++w) {
        int idx = w * 64 + lane; int cc = idx >> 5, rr = idx & 31;
        C[(aJ + cc) * NN + aI + rr] = Vtc[cc][rr];
    }
    __threadfence();
    if (lane == 0) stflag(flags, I, J);
}

// ---------------------------------------------------------------------------
// Traceback (R2 version — known 505 us). Stack entries carry v; block-wide
// first-max argmax for split events.
// ---------------------------------------------------------------------------
__global__ __launch_bounds__(256) void traceback_kernel(const double* __restrict__ R,
                                                        const double* __restrict__ C,
                                                        const float* __restrict__ S,
                                                        float* __restrict__ out) {
    __shared__ int stk_i[2048];
    __shared__ int stk_j[2048];
    __shared__ double stk_v[2048];
    __shared__ int sh_top, sh_ii, sh_jj, sh_cmd;
    __shared__ double sred_v[4];
    __shared__ int sred_k[4];
    const double eps = 1e-9;
    if (threadIdx.x == 0) {
        sh_top = 1; stk_i[0] = 0; stk_j[0] = NN - 1; stk_v[0] = R[NN - 1];
    }
    __syncthreads();
    while (true) {
        if (threadIdx.x == 0) {
            int cmd = -1, top = sh_top;
            while (top > 0) {
                int i = stk_i[--top];
                int j = stk_j[top];
                double v = stk_v[top];
                if (j <= i) continue;
                if (v <= eps) continue;
                double a = R[(i + 1) * NN + j];
                float sv = S[i * NN + j];
                double b2 = R[(i + 1) * NN + j - 1];
                if (a >= v - eps) {
                    stk_i[top] = i + 1; stk_j[top] = j; stk_v[top] = a; ++top;
                } else if (sv > 0.0f && b2 + (double)sv >= v - eps) {
                    out[i * NN + j] = sv; out[j * NN + i] = sv;
                    stk_i[top] = i + 1; stk_j[top] = j - 1; stk_v[top] = b2; ++top;
                } else {
                    sh_ii = i; sh_jj = j; cmd = 0; break;
                }
            }
            sh_top = top; sh_cmd = cmd;
        }
        __syncthreads();
        if (sh_cmd < 0) break;
        int i = sh_ii, j = sh_jj;
        double bv = -1.0; int bk = 0x7fffffff;
        for (int k = i + threadIdx.x; k < j; k += 256) {
            double tv = R[i * NN + k] + C[j * NN + k + 1];
            if (tv > bv) { bv = tv; bk = k; }
        }
        for (int off = 32; off; off >>= 1) {
            double ov = __shfl_down(bv, off);
            int   ok = __shfl_down(bk, off);
            if (ov > bv || (ov == bv && ok < bk)) { bv = ov; bk = ok; }
        }
        if ((threadIdx.x & 63) == 0) { sred_v[threadIdx.x >> 6] = bv; sred_k[threadIdx.x >> 6] = bk; }
        __syncthreads();
        if (threadIdx.x == 0) {
            double fv = sred_v[0]; int fk = sred_k[0];
            for (int w = 1; w < 4; ++w)
                if (sred_v[w] > fv || (sred_v[w] == fv && sred_k[w] < fk)) { fv = sred_v[w]; fk = sred_k[w]; }
            int top = sh_top;
            stk_i[top] = sh_ii;   stk_j[top] = fk;    stk_v[top] = R[sh_ii * NN + fk];   ++top;
            stk_i[top] = fk + 1;  stk_j[top] = sh_jj; stk_v[top] = C[sh_jj * NN + fk + 1]; ++top;
            sh_top = top;
        }
        __syncthreads();
    }
}

// ---------------------------------------------------------------------------
extern "C" void kernel_launch(void* const* d_in, const int* in_sizes, int n_in,
                              void* d_out, int out_size, void* d_ws, size_t ws_size,
                              hipStream_t stream) {
    const float* con  = (const float*)d_in[0];
    const float* feat = (const float*)d_in[1];
    float* out = (float*)d_out;

    char* ws = (char*)d_ws;
    double* R      = (double*)(ws);
    double* C      = (double*)(ws + (size_t)8  * 1024 * 1024);
    float*  S      = (float*) (ws + (size_t)16 * 1024 * 1024);
    int*    primes = (int*)   (ws + (size_t)20 * 1024 * 1024);
    int*    flags  = (int*)   (ws + (size_t)20 * 1024 * 1024 + 8192);

    primes_kernel<<<(NN + 255) / 256, 256, 0, stream>>>(feat, primes);
    prep_kernel<<<(NN * NN) / 256, 256, 0, stream>>>(con, primes, S, R, C, out, flags);
    nuss_tiles_kernel<<<NTILES, 64, 0, stream>>>(R, C, S, flags);
    traceback_kernel<<<1, 256, 0, stream>>>(R, C, S, out);
}

// Round 5
// 2151.242 us; speedup vs baseline: 1.8589x; 1.1842x over previous
//
#include <hip/hip_runtime.h>
#include <hip/hip_bf16.h>

#define NN 1024
#define BT 32
#define TT 32
#define NTILES ((TT * (TT + 1)) / 2)   // 528

// ---------------------------------------------------------------------------
// Flags: 64B-padded, relaxed polls + single acquire fence (no per-poll inv).
// ---------------------------------------------------------------------------
__device__ __forceinline__ void waitflag(const int* f, int a, int b) {
    const int* p = &f[(a * TT + b) << 4];
    while (!__hip_atomic_load(p, __ATOMIC_RELAXED, __HIP_MEMORY_SCOPE_AGENT))
        __builtin_amdgcn_s_sleep(1);
    __builtin_amdgcn_fence(__ATOMIC_ACQUIRE, "agent");
}
__device__ __forceinline__ void setflag(int* f, int a, int b) {
    __hip_atomic_store(&f[(a * TT + b) << 4], 1, __ATOMIC_RELEASE, __HIP_MEMORY_SCOPE_AGENT);
}

// ---------------------------------------------------------------------------
__global__ void primes_kernel(const float* __restrict__ feat, int* __restrict__ primes) {
    int i = blockIdx.x * blockDim.x + threadIdx.x;
    if (i < NN) {
        float best = feat[i * NN];
        int arg = 0;
        for (int ch = 1; ch < 4; ++ch) {
            float v = feat[ch * NN * NN + i * NN];
            if (v > best) { best = v; arg = ch; }
        }
        const int P[4] = {2, 3, 5, 7};
        primes[i] = P[arg];
    }
}

__global__ void prep_kernel(const float* __restrict__ con, const int* __restrict__ primes,
                            float* __restrict__ S, double* __restrict__ R,
                            double* __restrict__ C, float* __restrict__ out,
                            int* __restrict__ flags) {
    int idx = blockIdx.x * blockDim.x + threadIdx.x;
    int i = idx >> 10;
    int j = idx & (NN - 1);
    float c = (con[idx] + con[j * NN + i]) * 0.5f;
    int prod = primes[i] * primes[j];
    bool canon = (prod == 14) | (prod == 15) | (prod == 35);
    int d = i - j; if (d < 0) d = -d;
    S[idx] = (canon && d >= 4) ? c : 0.0f;
    R[idx] = 0.0;
    C[idx] = 0.0;
    out[idx] = 0.0f;
    if (idx < TT * TT * 16) flags[idx] = 0;
}

// ---------------------------------------------------------------------------
// Dataflow DP, one wave per 32x32 tile. Exactness: every candidate is one
// fp64 add of stored values; extra candidates are dominated (-1e30+x<0<=dp,
// stale-0 + 0 = 0 <= dp). fmax order-insensitive => DP bitwise == numpy.
// Vtc/DJJc stride 33 doubles -> 2-way LDS banking (free). Vtc[c][32] holds
// the edge row V(aI+32, aJ+c) so the left-split loop covers k=aI+31.
// ---------------------------------------------------------------------------
__global__ __launch_bounds__(64) void nuss_tiles_kernel(double* __restrict__ R,
                                                        double* __restrict__ C,
                                                        const float* __restrict__ S,
                                                        int* __restrict__ flags) {
    __shared__ double DJJc[32][33];                         // DJJc[c][m]=V(aJ+m,aJ+c); [32]=0
    __shared__ double Vtc[32][33];                          // Vtc[c][r]=V(aI+r,aJ+c); [32]=edge
    __shared__ __attribute__((aligned(16))) double Ast[32][34]; // Ast[kk][r]=V(aI+r,kt0+kk)
    __shared__ __attribute__((aligned(16))) double Bst[32][34]; // Bst[kk][c]=V(kt0+kk+1,aJ+c)
    __shared__ double Pld[32][33];
    __shared__ float  Sld[32][32];
    __shared__ double edgeCol[33];                          // V(aI+rr, aJ-1)

    int b = blockIdx.x, dd = 0;
    while (b >= TT - dd) { b -= TT - dd; ++dd; }
    const int I = b, J = b + dd;
    const int aI = I * BT, aJ = J * BT;
    const int lane = threadIdx.x;
    const int r = lane >> 1;
    const int h = lane & 1;

    if (dd == 0) {
        // ---------------- diagonal tile ----------------
        for (int w = 0; w < 16; ++w) {
            int idx = w * 64 + lane; int rr = idx >> 5, cc = idx & 31;
            Sld[rr][cc] = S[(aI + rr) * NN + aI + cc];
        }
        for (int idx = lane; idx < 32 * 33; idx += 64)
            ((double*)Vtc)[idx] = 0.0;
        double vrow[16];
        #pragma unroll
        for (int u = 0; u < 16; ++u) vrow[u] = 0.0;

        for (int s = 1; s <= 31; ++s) {
            int c = r + s;
            bool act = (c <= 31);
            double acc = 0.0;
            if (act) {
                double t0 = 0.0, t1 = 0.0, t2 = 0.0, t3 = 0.0;
                #pragma unroll
                for (int u = 0; u < 16; u += 4) {
                    int k0 = h * 16 + u;
                    t0 = fmax(t0, vrow[u]     + Vtc[c][k0 + 1]);
                    t1 = fmax(t1, vrow[u + 1] + Vtc[c][k0 + 2]);
                    t2 = fmax(t2, vrow[u + 2] + Vtc[c][k0 + 3]);
                    t3 = fmax(t3, vrow[u + 3] + Vtc[c][k0 + 4]);
                }
                acc = fmax(fmax(t0, t1), fmax(t2, t3));
            }
            acc = fmax(acc, __shfl_xor(acc, 1));
            if (act) {
                double best = fmax(acc, Vtc[c - 1][r + 1] + (double)Sld[r][c]);
                if (h == 0) Vtc[c][r] = best;
                #pragma unroll
                for (int u = 0; u < 16; ++u)
                    if (h * 16 + u == c) vrow[u] = best;
            }
        }
        for (int w = 0; w < 16; ++w) {
            int idx = w * 64 + lane; int rr = idx >> 5, cc = idx & 31;
            R[(aI + rr) * NN + aI + cc] = Vtc[cc][rr];
        }
        for (int w = 0; w < 16; ++w) {
            int idx = w * 64 + lane; int cc = idx >> 5, rr = idx & 31;
            C[(aI + cc) * NN + aI + rr] = Vtc[cc][rr];
        }
        if (lane == 0) setflag(flags, I, I);
        return;
    }

    // ---------------- off-diagonal tile ----------------
    waitflag(flags, I, I);
    waitflag(flags, J, J);

    for (int w = 0; w < 16; ++w) {
        int idx = w * 64 + lane; int cc = idx >> 5, mm = idx & 31;
        DJJc[cc][mm] = C[(aJ + cc) * NN + aJ + mm];
    }
    if (lane < 32) DJJc[lane][32] = 0.0;
    for (int w = 0; w < 16; ++w) {
        int idx = w * 64 + lane; int rr = idx >> 5, cc = idx & 31;
        Sld[rr][cc] = S[(aI + rr) * NN + aJ + cc];
    }
    for (int idx = lane; idx < 32 * 33; idx += 64)
        ((double*)Vtc)[idx] = 0.0;

    double aslice[16];
    #pragma unroll
    for (int u = 0; u < 16; ++u) {
        int kk = h * 16 + u;
        aslice[u] = (kk >= r) ? R[(aI + r) * NN + aI + kk] : -1.0e30;
    }

    // ---- phaseA: deterministic middle-out k-tile order ----
    double P[16];
    #pragma unroll
    for (int x = 0; x < 16; ++x) P[x] = 0.0;
    const int nk = dd - 1;
    const int rg = lane >> 3, cg = lane & 7;
    const int r4 = rg * 4, c4 = cg * 4;
    int tl = (I + J) >> 1, tr = ((I + J) >> 1) + 1;
    for (int q = 0; q < nk; ++q) {
        int t;
        if ((q & 1) == 0) { if (tl >= I + 1) t = tl--; else t = tr++; }
        else              { if (tr <= J - 1) t = tr++; else t = tl--; }
        waitflag(flags, I, t);
        waitflag(flags, t, J);          // implies (t+1, J) done too
        int kt0 = t * BT;
        for (int w = 0; w < 16; ++w) {
            int idx = w * 64 + lane; int rr = idx >> 5, kk = idx & 31;
            Ast[kk][rr] = R[(aI + rr) * NN + kt0 + kk];
            Bst[kk][rr] = C[(aJ + rr) * NN + kt0 + 1 + kk];
        }
        for (int kk = 0; kk < 32; ++kk) {
            double2 av0 = *(const double2*)&Ast[kk][r4];
            double2 av1 = *(const double2*)&Ast[kk][r4 + 2];
            double2 bv0 = *(const double2*)&Bst[kk][c4];
            double2 bv1 = *(const double2*)&Bst[kk][c4 + 2];
            P[0]  = fmax(P[0],  av0.x + bv0.x); P[1]  = fmax(P[1],  av0.x + bv0.y);
            P[2]  = fmax(P[2],  av0.x + bv1.x); P[3]  = fmax(P[3],  av0.x + bv1.y);
            P[4]  = fmax(P[4],  av0.y + bv0.x); P[5]  = fmax(P[5],  av0.y + bv0.y);
            P[6]  = fmax(P[6],  av0.y + bv1.x); P[7]  = fmax(P[7],  av0.y + bv1.y);
            P[8]  = fmax(P[8],  av1.x + bv0.x); P[9]  = fmax(P[9],  av1.x + bv0.y);
            P[10] = fmax(P[10], av1.x + bv1.x); P[11] = fmax(P[11], av1.x + bv1.y);
            P[12] = fmax(P[12], av1.y + bv0.x); P[13] = fmax(P[13], av1.y + bv0.y);
            P[14] = fmax(P[14], av1.y + bv1.x); P[15] = fmax(P[15], av1.y + bv1.y);
        }
    }
    if (nk > 0) {
        #pragma unroll
        for (int x = 0; x < 4; ++x)
            #pragma unroll
            for (int y = 0; y < 4; ++y)
                Pld[r4 + x][c4 + y] = P[x * 4 + y];
    } else {
        for (int idx = lane; idx < 32 * 33; idx += 64)
            ((double*)Pld)[idx] = 0.0;
    }

    // ---- edges (flags covered: dd==1 by diag waits; dd>=2 by k-loop) ----
    if (lane < 33) edgeCol[lane] = R[(aI + lane) * NN + (aJ - 1)];
    if (lane < 32) Vtc[lane][32] = R[(aI + 32) * NN + aJ + lane];

    // ---- phaseB: 63 anti-diagonal micro-steps, barrier-free ----
    double vrow[16];
    #pragma unroll
    for (int u = 0; u < 16; ++u) vrow[u] = 0.0;

    for (int s = 0; s < 63; ++s) {
        int c = r + s - 31;
        bool act = ((unsigned)c < 32u);
        double acc = -1.0e30;
        if (act) {
            double t0 = -1.0e30, t1 = -1.0e30, t2 = -1.0e30, t3 = -1.0e30;
            #pragma unroll
            for (int u = 0; u < 16; u += 4) {
                int k0 = h * 16 + u;
                t0 = fmax(t0, aslice[u]     + Vtc[c][k0 + 1]);
                t1 = fmax(t1, aslice[u + 1] + Vtc[c][k0 + 2]);
                t2 = fmax(t2, aslice[u + 2] + Vtc[c][k0 + 3]);
                t3 = fmax(t3, aslice[u + 3] + Vtc[c][k0 + 4]);
            }
            double q0 = -1.0e30, q1 = -1.0e30, q2 = -1.0e30, q3 = -1.0e30;
            #pragma unroll
            for (int u = 0; u < 16; u += 4) {
                int m0 = h * 16 + u + 1;
                q0 = fmax(q0, vrow[u]     + DJJc[c][m0]);
                q1 = fmax(q1, vrow[u + 1] + DJJc[c][m0 + 1]);
                q2 = fmax(q2, vrow[u + 2] + DJJc[c][m0 + 2]);
                q3 = fmax(q3, vrow[u + 3] + DJJc[c][m0 + 3]);
            }
            acc = fmax(fmax(fmax(t0, t1), fmax(t2, t3)),
                       fmax(fmax(q0, q1), fmax(q2, q3)));
        }
        acc = fmax(acc, __shfl_xor(acc, 1));
        if (act) {
            double best = acc;
            best = fmax(best, edgeCol[r] + DJJc[c][0]);      // k = aJ-1
            best = fmax(best, Pld[r][c]);                    // external k-tiles
            double pv = (c > 0) ? Vtc[c - 1][r + 1] : edgeCol[r + 1];
            best = fmax(best, pv + (double)Sld[r][c]);       // pair
            if (h == 0) Vtc[c][r] = best;
            #pragma unroll
            for (int u = 0; u < 16; ++u)
                if (h * 16 + u == c) vrow[u] = best;
        }
    }

    for (int w = 0; w < 16; ++w) {
        int idx = w * 64 + lane; int rr = idx >> 5, cc = idx & 31;
        R[(aI + rr) * NN + aJ + cc] = Vtc[cc][rr];
    }
    for (int w = 0; w < 16; ++w) {
        int idx = w * 64 + lane; int cc = idx >> 5, rr = idx & 31;
        C[(aJ + cc) * NN + aI + rr] = Vtc[cc][rr];
    }
    if (lane == 0) setflag(flags, I, J);
}

// ---------------------------------------------------------------------------
// Traceback, software-pipelined: successor operands are loaded BEFORE the
// branch decision, hiding one L2 latency per event. Semantics unchanged.
// ---------------------------------------------------------------------------
__global__ __launch_bounds__(256) void traceback_kernel(const double* __restrict__ R,
                                                        const double* __restrict__ C,
                                                        const float* __restrict__ S,
                                                        float* __restrict__ out) {
    __shared__ int stk_i[2048];
    __shared__ int stk_j[2048];
    __shared__ double stk_v[2048];
    __shared__ int sh_top, sh_ii, sh_jj, sh_cmd;
    __shared__ double sred_v[4];
    __shared__ int sred_k[4];
    const double eps = 1e-9;
    if (threadIdx.x == 0) {
        sh_top = 1; stk_i[0] = 0; stk_j[0] = NN - 1; stk_v[0] = R[NN - 1];
    }
    __syncthreads();
    while (true) {
        if (threadIdx.x == 0) {
            int cmd = -1, top = sh_top;
            int i = 0, j = 0; double v = 0.0, a = 0.0, b2 = 0.0; float sv = 0.0f;
            bool have = false;
            while (true) {
                if (!have) {
                    if (top == 0) { cmd = -1; break; }
                    i = stk_i[--top]; j = stk_j[top]; v = stk_v[top];
                    if (j <= i || v <= eps) continue;
                    a  = R[(i + 1) * NN + j];
                    sv = S[i * NN + j];
                    b2 = R[(i + 1) * NN + j - 1];
                    have = true;
                    continue;
                }
                int ip = (i + 2 <= NN - 1) ? i + 2 : NN - 1;    // clamp (unused if OOB)
                int jl = (j - 2 >= 0) ? j - 2 : 0;
                double ar = R[ip * NN + j];
                double br = R[ip * NN + j - 1];
                double bl = R[ip * NN + jl];
                float  sr = S[(i + 1) * NN + j];
                float  sl = S[(i + 1) * NN + j - 1];
                if (a >= v - eps) {
                    ++i; v = a; a = ar; sv = sr; b2 = br;
                    if (j <= i || v <= eps) have = false;
                    continue;
                }
                if (sv > 0.0f && b2 + (double)sv >= v - eps) {
                    out[i * NN + j] = sv; out[j * NN + i] = sv;
                    ++i; --j; v = b2; a = br; sv = sl; b2 = bl;
                    if (j <= i || v <= eps) have = false;
                    continue;
                }
                sh_ii = i; sh_jj = j; cmd = 0; break;
            }
            sh_top = top; sh_cmd = cmd;
        }
        __syncthreads();
        if (sh_cmd < 0) break;
        int i = sh_ii, j = sh_jj;
        double bv = -1.0; int bk = 0x7fffffff;
        for (int k = i + threadIdx.x; k < j; k += 256) {
            double tv = R[i * NN + k] + C[j * NN + k + 1];
            if (tv > bv) { bv = tv; bk = k; }
        }
        for (int off = 32; off; off >>= 1) {
            double ov = __shfl_down(bv, off);
            int   ok = __shfl_down(bk, off);
            if (ov > bv || (ov == bv && ok < bk)) { bv = ov; bk = ok; }
        }
        if ((threadIdx.x & 63) == 0) { sred_v[threadIdx.x >> 6] = bv; sred_k[threadIdx.x >> 6] = bk; }
        __syncthreads();
        if (threadIdx.x == 0) {
            double fv = sred_v[0]; int fk = sred_k[0];
            for (int w = 1; w < 4; ++w)
                if (sred_v[w] > fv || (sred_v[w] == fv && sred_k[w] < fk)) { fv = sred_v[w]; fk = sred_k[w]; }
            int top = sh_top;
            stk_i[top] = sh_ii;  stk_j[top] = fk;    stk_v[top] = R[sh_ii * NN + fk];      ++top;
            stk_i[top] = fk + 1; stk_j[top] = sh_jj; stk_v[top] = C[sh_jj * NN + fk + 1];  ++top;
            sh_top = top;
        }
        __syncthreads();
    }
}

// ---------------------------------------------------------------------------
extern "C" void kernel_launch(void* const* d_in, const int* in_sizes, int n_in,
                              void* d_out, int out_size, void* d_ws, size_t ws_size,
                              hipStream_t stream) {
    const float* con  = (const float*)d_in[0];
    const float* feat = (const float*)d_in[1];
    float* out = (float*)d_out;

    char* ws = (char*)d_ws;
    double* R      = (double*)(ws);
    double* C      = (double*)(ws + (size_t)8  * 1024 * 1024);
    float*  S      = (float*) (ws + (size_t)16 * 1024 * 1024);
    int*    primes = (int*)   (ws + (size_t)20 * 1024 * 1024);
    int*    flags  = (int*)   (ws + (size_t)20 * 1024 * 1024 + 8192);

    primes_kernel<<<(NN + 255) / 256, 256, 0, stream>>>(feat, primes);
    prep_kernel<<<(NN * NN) / 256, 256, 0, stream>>>(con, primes, S, R, C, out, flags);
    nuss_tiles_kernel<<<NTILES, 64, 0, stream>>>(R, C, S, flags);
    traceback_kernel<<<1, 256, 0, stream>>>(R, C, S, out);
}